// Round 15
// baseline (288.269 us; speedup 1.0000x reference)
//
#include <hip/hip_runtime.h>
#include <hip/hip_bf16.h>

// FEAT=EMB=HID=64, VOCAB=32, N_GRAPHS=64. N,E from in_sizes.
// R6: transform-first. R7: binned CSR. R9: padded CSR + mask-free gather.
// R11: fp8 e4m3 gather table (64B rows = 1 line), quarter-wave dword gather.
// R13/R14: gemm1 fused into binning kernel; B-frags self-built from fp32.
// R15: finalize writes pad-tails only (no full dummy-init double-write);
// pool+head merged via last-block pattern (threadfence + done counter;
// winner reads pooled via device-scope atomicAdd(p,0) for XCD coherence).

typedef __attribute__((ext_vector_type(8))) short short8;
typedef __attribute__((ext_vector_type(4))) float f32x4;
typedef __attribute__((ext_vector_type(2))) float f32x2;

#define RB 9            // 512 nodes per coarse bin
#define MAXBINS 256     // N <= 131072
#define CAP 12288       // coarse per-bin capacity
#define BCAP 14336      // padded per-bin bucket capacity
#define CHUNK 8192      // edges per bin block

__device__ inline float bf2f(unsigned short h) {
    return __uint_as_float(((unsigned int)h) << 16);
}
__device__ inline float bflo(unsigned int u) { return __uint_as_float(u << 16); }
__device__ inline float bfhi(unsigned int u) { return __uint_as_float(u & 0xffff0000u); }
__device__ inline unsigned short f2bf(float f) {
    unsigned int u = __float_as_uint(f);
    u = (u + 0x7fffu + ((u >> 16) & 1u)) >> 16;  // RNE
    return (unsigned short)u;
}

// Self-build MFMA B-fragments from fp32 W (cols 0..63) and R (cols 64..127).
__device__ inline void build_bfrag(const float* __restrict__ W,
                                   const float* __restrict__ R,
                                   int q, int mm, short8 bfrag[8][2]) {
#pragma unroll
    for (int t = 0; t < 8; ++t) {
        const int n = t * 16 + mm;
        const float* P = (n < 64) ? (W + n) : (R + n - 64);
#pragma unroll
        for (int c = 0; c < 2; ++c) {
#pragma unroll
            for (int j = 0; j < 8; ++j) {
                const int k = c * 32 + q * 8 + j;
                bfrag[t][c][j] = (short)f2bf(P[k * 64]);
            }
        }
    }
}

// fp8 epilogue store: lanes mm%4==0 pack 4 n-columns into one dword.
__device__ inline void store_xw_fp8(unsigned char* __restrict__ xw8, int rowbase, int q,
                                    int t, int mm, const f32x4& accT, int N) {
#pragma unroll
    for (int r = 0; r < 4; ++r) {
        const float v0 = accT[r];
        const float v1 = __shfl_down(v0, 1);
        const float v2 = __shfl_down(v0, 2);
        const float v3 = __shfl_down(v0, 3);
        const int orow = rowbase + q * 4 + r;
        if (!(mm & 3) && orow < N) {
            unsigned int u = (unsigned int)__builtin_amdgcn_cvt_pk_fp8_f32(v0, v1, 0, false);
            u = (unsigned int)__builtin_amdgcn_cvt_pk_fp8_f32(v2, v3, (int)u, true);
            *(unsigned int*)&xw8[(size_t)orow * 64 + t * 16 + mm] = u;
        }
    }
}

// ---------------- K1: bin edges (blocks [0,nbBin)) + gemm1 (rest) -----------
__global__ __launch_bounds__(256) void bin_gemm1(const int* __restrict__ src,
                                                 const int* __restrict__ dst,
                                                 unsigned int* __restrict__ coarse,
                                                 int* __restrict__ gcur,
                                                 int E, int BINS, int nbBin,
                                                 const float* __restrict__ x,
                                                 const float* __restrict__ W1,
                                                 const float* __restrict__ R1,
                                                 const float* __restrict__ bias,
                                                 unsigned char* __restrict__ xw8,
                                                 unsigned short* __restrict__ xrb,
                                                 int N) {
    __shared__ int cnt[MAXBINS];
    __shared__ int incl[MAXBINS];
    __shared__ int bstart[MAXBINS];
    __shared__ int bcur[MAXBINS];
    __shared__ int gbase[MAXBINS];
    __shared__ unsigned int stage[CHUNK];
    __shared__ unsigned char binOf[CHUNK];

    const int tid = threadIdx.x;
    if (blockIdx.x >= (unsigned)nbBin) {
        // ---- gemm1 branch: xw8/xrb = x @ [W1|R1] (+b1 in R half) ----
        const int gb = blockIdx.x - nbBin;
        if (gb == 0 && tid < 16)  // zero fp8 row N (dummy target)
            *(unsigned int*)&xw8[(size_t)N * 64 + tid * 4] = 0u;

        const int lane = tid & 63;
        const int q = lane >> 4;
        const int mm = lane & 15;

        short8 bfrag[8][2];
        build_bfrag(W1, R1, q, mm, bfrag);
        float bv[4];
#pragma unroll
        for (int tt = 0; tt < 4; ++tt) bv[tt] = bias[tt * 16 + mm];

        const int wid = tid >> 6;
        const int gw = gb * 4 + wid;
        const int nw = 1024 * 4;
        const int ntiles = N >> 4;

        for (int tile = gw; tile < ntiles; tile += nw) {
            const int row0 = tile << 4;
            const float* ap = &x[(size_t)(row0 + mm) * 64 + q * 8];
            const float4 f0 = *(const float4*)ap;
            const float4 f1 = *(const float4*)(ap + 4);
            const float4 f2 = *(const float4*)(ap + 32);
            const float4 f3 = *(const float4*)(ap + 36);
            short8 a0, a1;
            a0[0] = (short)f2bf(f0.x); a0[1] = (short)f2bf(f0.y);
            a0[2] = (short)f2bf(f0.z); a0[3] = (short)f2bf(f0.w);
            a0[4] = (short)f2bf(f1.x); a0[5] = (short)f2bf(f1.y);
            a0[6] = (short)f2bf(f1.z); a0[7] = (short)f2bf(f1.w);
            a1[0] = (short)f2bf(f2.x); a1[1] = (short)f2bf(f2.y);
            a1[2] = (short)f2bf(f2.z); a1[3] = (short)f2bf(f2.w);
            a1[4] = (short)f2bf(f3.x); a1[5] = (short)f2bf(f3.y);
            a1[6] = (short)f2bf(f3.z); a1[7] = (short)f2bf(f3.w);
            f32x4 acc[8];
#pragma unroll
            for (int t = 0; t < 8; ++t) {
                acc[t] = (f32x4){0.f, 0.f, 0.f, 0.f};
                acc[t] = __builtin_amdgcn_mfma_f32_16x16x32_bf16(a0, bfrag[t][0], acc[t], 0, 0, 0);
                acc[t] = __builtin_amdgcn_mfma_f32_16x16x32_bf16(a1, bfrag[t][1], acc[t], 0, 0, 0);
            }
#pragma unroll
            for (int t = 0; t < 4; ++t) store_xw_fp8(xw8, row0, q, t, mm, acc[t], N);
#pragma unroll
            for (int t = 4; t < 8; ++t) {
#pragma unroll
                for (int r = 0; r < 4; ++r) {
                    const float v = acc[t][r] + bv[t - 4];
                    const float vn = __shfl_down(v, 1);
                    if (!(mm & 1)) {
                        const unsigned int u = (unsigned int)f2bf(v) | ((unsigned int)f2bf(vn) << 16);
                        *(unsigned int*)&xrb[(size_t)(row0 + q * 4 + r) * 64 + (t - 4) * 16 + mm] = u;
                    }
                }
            }
        }
        return;
    }

    // ---- binning branch ----
    const int chunk0 = blockIdx.x * CHUNK;
    int myS[32], myD[32];
#pragma unroll
    for (int k = 0; k < 32; ++k) {
        const int idx = chunk0 + k * 256 + tid;
        if (idx < E) { myS[k] = src[idx]; myD[k] = dst[idx]; }
        else myD[k] = -1;
    }
    cnt[tid] = 0;
    __syncthreads();
#pragma unroll
    for (int k = 0; k < 32; ++k)
        if (myD[k] >= 0) atomicAdd(&cnt[myD[k] >> RB], 1);
    __syncthreads();
    incl[tid] = cnt[tid];
    __syncthreads();
    for (int off = 1; off < 256; off <<= 1) {
        int t = (tid >= off) ? incl[tid - off] : 0;
        __syncthreads();
        incl[tid] += t;
        __syncthreads();
    }
    bstart[tid] = incl[tid] - cnt[tid];
    bcur[tid] = incl[tid] - cnt[tid];
    __syncthreads();
#pragma unroll
    for (int k = 0; k < 32; ++k) {
        if (myD[k] >= 0) {
            const int b = myD[k] >> RB;
            const int pos = atomicAdd(&bcur[b], 1);
            stage[pos] = (unsigned int)myS[k] | ((unsigned int)(myD[k] & ((1 << RB) - 1)) << 17);
            binOf[pos] = (unsigned char)b;
        }
    }
    __syncthreads();
    if (tid < BINS && cnt[tid] > 0)
        gbase[tid] = tid * CAP + atomicAdd(&gcur[tid], cnt[tid]);
    __syncthreads();
    int total = E - chunk0;
    if (total > CHUNK) total = CHUNK;
    for (int idx = tid; idx < total; idx += 256) {
        const int b = binOf[idx];
        coarse[gbase[b] + (idx - bstart[b])] = stage[idx];
    }
}

// ---------------- K2: finalize padded CSR (one block per bin) ---------------
// Pad-tails written directly (disjoint from scatter positions) — no full
// dummy-init double-write.
__global__ __launch_bounds__(256) void finalize_csr(const unsigned int* __restrict__ coarse,
                                                    const int* __restrict__ gcur,
                                                    int* __restrict__ bucket,
                                                    int* __restrict__ pstart,
                                                    int* __restrict__ degarr,
                                                    int N, int BINS) {
    __shared__ int ncnt[512];
    __shared__ int pexcl[512];
    __shared__ int ncur[512];
    __shared__ int s2[256];

    const int tid = threadIdx.x;
    const int b = blockIdx.x;
    const int cb = gcur[b];
    const int base = b * BCAP;
    const unsigned int* reg = coarse + (size_t)b * CAP;
    const int node0 = b << RB;
    int nloc = N - node0;
    if (nloc > 512) nloc = 512;

    ncnt[tid] = 0; ncnt[tid + 256] = 0;
    __syncthreads();
    for (int idx = tid; idx < cb; idx += 256)
        atomicAdd(&ncnt[reg[idx] >> 17], 1);
    __syncthreads();
    const int p0 = (ncnt[2 * tid] + 15) & ~15;
    const int p1 = (ncnt[2 * tid + 1] + 15) & ~15;
    s2[tid] = p0 + p1;
    __syncthreads();
    for (int off = 1; off < 256; off <<= 1) {
        int t = (tid >= off) ? s2[tid - off] : 0;
        __syncthreads();
        s2[tid] += t;
        __syncthreads();
    }
    const int pairExcl = s2[tid] - (p0 + p1);
    pexcl[2 * tid] = pairExcl;
    pexcl[2 * tid + 1] = pairExcl + p0;
    ncur[2 * tid] = pairExcl;
    ncur[2 * tid + 1] = pairExcl + p0;
    __syncthreads();
    for (int i = tid; i < nloc; i += 256) {
        pstart[node0 + i] = base + pexcl[i];
        degarr[node0 + i] = ncnt[i];
        // pad tail [excl+deg, excl+pdeg) -> dummy row N (disjoint from scatter)
        const int dg = ncnt[i];
        const int pd = (dg + 15) & ~15;
        for (int j = dg; j < pd; ++j) bucket[base + pexcl[i] + j] = N;
    }
    for (int idx = tid; idx < cb; idx += 256) {
        const unsigned int e = reg[idx];
        const int p = atomicAdd(&ncur[e >> 17], 1);
        bucket[base + p] = (int)(e & 0x1FFFFu);
    }
}

// ---------------- K3/K5: aggregate: out = relu(mean_j xW[j] + xRb[i]) -------
__global__ __launch_bounds__(256) void aggregate(const unsigned char* __restrict__ xw8,
                                                 const unsigned short* __restrict__ xrb,
                                                 const int* __restrict__ pstart,
                                                 const int* __restrict__ degarr,
                                                 const int* __restrict__ bucket,
                                                 unsigned short* __restrict__ outb,
                                                 int N) {
    const int lane = threadIdx.x & 63;
    const int quarter = lane >> 4;
    const int fl = lane & 15;
    const int wid = threadIdx.x >> 6;
    const int gw = blockIdx.x * 4 + wid;
    const int nw = gridDim.x * 4;

    for (int i = gw; i < N; i += nw) {
        const int r0 = pstart[i];
        const int dg = degarr[i];
        const int pdeg = (dg + 15) & ~15;
        float a0 = 0.f, a1 = 0.f, a2 = 0.f, a3 = 0.f;
        for (int base = 0; base < pdeg; base += 64) {
            const int rem = pdeg - base;
            const int s = (lane < rem) ? bucket[r0 + base + lane] : N;
            const int mm = rem < 64 ? rem : 64;
            for (int t = 0; t < mm; t += 16) {
                unsigned int u[4];
#pragma unroll
                for (int p = 0; p < 4; ++p) {
                    const int rr = __shfl(s, t + 4 * p + quarter);
                    u[p] = *(const unsigned int*)&xw8[(size_t)rr * 64 + fl * 4];
                }
#pragma unroll
                for (int p = 0; p < 4; ++p) {
                    const f32x2 lo = __builtin_amdgcn_cvt_pk_f32_fp8(u[p], false);
                    const f32x2 hi = __builtin_amdgcn_cvt_pk_f32_fp8(u[p], true);
                    a0 += lo.x; a1 += lo.y; a2 += hi.x; a3 += hi.y;
                }
            }
        }
        a0 += __shfl_xor(a0, 16); a1 += __shfl_xor(a1, 16);
        a2 += __shfl_xor(a2, 16); a3 += __shfl_xor(a3, 16);
        a0 += __shfl_xor(a0, 32); a1 += __shfl_xor(a1, 32);
        a2 += __shfl_xor(a2, 32); a3 += __shfl_xor(a3, 32);

        const float inv = 1.0f / (float)(dg > 0 ? dg : 1);
        if (quarter == 0) {
            const uint2 ur = *(const uint2*)&xrb[(size_t)i * 64 + fl * 4];
            const float o0 = fmaxf(a0 * inv + bflo(ur.x), 0.f);
            const float o1 = fmaxf(a1 * inv + bfhi(ur.x), 0.f);
            const float o2 = fmaxf(a2 * inv + bflo(ur.y), 0.f);
            const float o3 = fmaxf(a3 * inv + bfhi(ur.y), 0.f);
            uint2 w;
            w.x = (unsigned int)f2bf(o0) | ((unsigned int)f2bf(o1) << 16);
            w.y = (unsigned int)f2bf(o2) | ((unsigned int)f2bf(o3) << 16);
            *(uint2*)&outb[(size_t)i * 64 + fl * 4] = w;
        }
    }
}

// ---------------- K4: gemm layer 2 (bf16 A from h1, self-built B) -----------
__global__ __launch_bounds__(256) void gemm_xwr2(const unsigned short* __restrict__ xin,
                                                 const float* __restrict__ W2,
                                                 const float* __restrict__ R2,
                                                 const float* __restrict__ bias,
                                                 unsigned char* __restrict__ xw8,
                                                 unsigned short* __restrict__ xrb,
                                                 int M) {
    if (blockIdx.x == 0 && threadIdx.x < 16)
        *(unsigned int*)&xw8[(size_t)M * 64 + threadIdx.x * 4] = 0u;

    const int lane = threadIdx.x & 63;
    const int q = lane >> 4;
    const int mm = lane & 15;

    short8 bfrag[8][2];
    build_bfrag(W2, R2, q, mm, bfrag);
    float bv[4];
#pragma unroll
    for (int tt = 0; tt < 4; ++tt) bv[tt] = bias[tt * 16 + mm];

    const int wid = threadIdx.x >> 6;
    const int gw = blockIdx.x * 4 + wid;
    const int nw = gridDim.x * 4;
    const int ntiles = M >> 4;

    for (int tile = gw; tile < ntiles; tile += nw) {
        const int row0 = tile << 4;
        const short8 a0 = *(const short8*)&xin[(size_t)(row0 + mm) * 64 + q * 8];
        const short8 a1 = *(const short8*)&xin[(size_t)(row0 + mm) * 64 + 32 + q * 8];
        f32x4 acc[8];
#pragma unroll
        for (int t = 0; t < 8; ++t) {
            acc[t] = (f32x4){0.f, 0.f, 0.f, 0.f};
            acc[t] = __builtin_amdgcn_mfma_f32_16x16x32_bf16(a0, bfrag[t][0], acc[t], 0, 0, 0);
            acc[t] = __builtin_amdgcn_mfma_f32_16x16x32_bf16(a1, bfrag[t][1], acc[t], 0, 0, 0);
        }
#pragma unroll
        for (int t = 0; t < 4; ++t) store_xw_fp8(xw8, row0, q, t, mm, acc[t], M);
#pragma unroll
        for (int t = 4; t < 8; ++t) {
#pragma unroll
            for (int r = 0; r < 4; ++r) {
                const float v = acc[t][r] + bv[t - 4];
                const float vn = __shfl_down(v, 1);
                if (!(mm & 1)) {
                    const unsigned int u = (unsigned int)f2bf(v) | ((unsigned int)f2bf(vn) << 16);
                    *(unsigned int*)&xrb[(size_t)(row0 + q * 4 + r) * 64 + (t - 4) * 16 + mm] = u;
                }
            }
        }
    }
}

// ---------------- K6: pooling + heads (last-block pattern) ------------------
// 64 blocks: block g computes pooled mean for graph g (plain stores), then
// __threadfence + atomicAdd(done). The last block to finish runs the head,
// reading pooled via device-scope atomicAdd(p,0) (coherent across XCD L2s).
__global__ __launch_bounds__(256) void pool_head(const unsigned short* __restrict__ h,
                                                 const int* __restrict__ batch,
                                                 float* __restrict__ pooled,
                                                 int* __restrict__ done, int N,
                                                 const float* __restrict__ Wh,
                                                 const float* __restrict__ bh,
                                                 const float* __restrict__ Wc,
                                                 const float* __restrict__ bc,
                                                 const float* __restrict__ Wo,
                                                 const float* __restrict__ bo,
                                                 float* __restrict__ out) {
    __shared__ float red[16][64];
    __shared__ int bnds[2];
    __shared__ float pm[4096];
    __shared__ float hid[4096];
    __shared__ float lg[2048];
    __shared__ int iwin;

    const int gph = blockIdx.x;
    const int t = threadIdx.x;
    if (t < 2) {
        const int target = gph + t;
        int lo = 0, hi = N;
        while (lo < hi) {
            int mid = (lo + hi) >> 1;
            if (batch[mid] < target) lo = mid + 1; else hi = mid;
        }
        bnds[t] = lo;
    }
    __syncthreads();
    const int r0 = bnds[0], r1 = bnds[1];
    const int f = t & 15;
    const int r = t >> 4;
    float4 acc = {0.f, 0.f, 0.f, 0.f};
    for (int row = r0 + r; row < r1; row += 16) {
        const ushort4 v = *(const ushort4*)&h[(size_t)row * 64 + f * 4];
        acc.x += bf2f(v.x); acc.y += bf2f(v.y);
        acc.z += bf2f(v.z); acc.w += bf2f(v.w);
    }
    red[r][f * 4 + 0] = acc.x; red[r][f * 4 + 1] = acc.y;
    red[r][f * 4 + 2] = acc.z; red[r][f * 4 + 3] = acc.w;
    __syncthreads();
    if (t < 64) {
        float s = 0.f;
        for (int j = 0; j < 16; ++j) s += red[j][t];
        const int cnt = r1 - r0;
        const float invc = 1.0f / (float)(cnt > 0 ? cnt : 1);
        pooled[gph * 64 + t] = s * invc;
    }
    __threadfence();
    __syncthreads();
    if (t == 0) {
        const int old = atomicAdd(done, 1);
        iwin = (old == 63) ? 1 : 0;
    }
    __syncthreads();
    if (!iwin) return;

    // ---- head phase (winner block only) ----
    for (int idx = t; idx < 4096; idx += 256)
        pm[idx] = atomicAdd(&pooled[idx], 0.0f);  // coherent read
    __syncthreads();

    for (int idx = t; idx < 4096; idx += 256) {
        int g = idx >> 6, o = idx & 63;
        float ah = bh[o], ac = bc[o];
        for (int k = 0; k < 64; ++k) {
            float p = pm[(g << 6) + k];
            ah += p * Wh[k * 64 + o];
            ac += p * Wc[k * 64 + o];
        }
        hid[idx] = ah;
        out[2048 + idx] = ah;
        out[6144 + idx] = ac;
    }
    __syncthreads();

    for (int idx = t; idx < 2048; idx += 256) {
        int g = idx >> 5, v = idx & 31;
        float a = bo[v];
        for (int k = 0; k < 64; ++k) a += hid[(g << 6) + k] * Wo[k * 32 + v];
        lg[idx] = a;
    }
    __syncthreads();

    if (t < 64) {
        float mx = -3.4e38f;
        for (int v = 0; v < 32; ++v) mx = fmaxf(mx, lg[(t << 5) + v]);
        float s = 0.f;
        for (int v = 0; v < 32; ++v) s += expf(lg[(t << 5) + v] - mx);
        float lse = mx + logf(s);
        for (int v = 0; v < 32; ++v) out[(t << 5) + v] = lg[(t << 5) + v] - lse;
    }
}

extern "C" void kernel_launch(void* const* d_in, const int* in_sizes, int n_in,
                              void* d_out, int out_size, void* d_ws, size_t ws_size,
                              hipStream_t stream) {
    const float* x = (const float*)d_in[0];
    const int* ei = (const int*)d_in[1];
    const int* batch = (const int*)d_in[2];
    const float* W1 = (const float*)d_in[3];
    const float* root1 = (const float*)d_in[4];
    const float* b1 = (const float*)d_in[5];
    const float* W2 = (const float*)d_in[6];
    const float* root2 = (const float*)d_in[7];
    const float* b2 = (const float*)d_in[8];
    const float* Wh = (const float*)d_in[9];
    const float* bh = (const float*)d_in[10];
    const float* Wc = (const float*)d_in[11];
    const float* bc = (const float*)d_in[12];
    const float* Wo = (const float*)d_in[13];
    const float* bo = (const float*)d_in[14];
    float* out = (float*)d_out;

    const int N = in_sizes[0] / 64;
    const int E = in_sizes[1] / 2;
    const int* srcp = ei;
    const int* dstp = ei + E;
    const int BINS = (N + (1 << RB) - 1) >> RB;

    char* ws = (char*)d_ws;
    size_t off = 0;
    auto alloc = [&](size_t bytes) -> void* {
        void* p = ws + off;
        off += (bytes + 255) & ~(size_t)255;
        return p;
    };
    int* pstart = (int*)alloc((size_t)N * 4);
    int* degarr = (int*)alloc((size_t)N * 4);
    int* bucket = (int*)alloc(((size_t)BINS * BCAP + 256) * 4);
    unsigned int* coarse = (unsigned int*)alloc((size_t)BINS * CAP * 4);
    unsigned short* h1 = (unsigned short*)alloc((size_t)N * 64 * 2);
    unsigned short* h2 = (unsigned short*)alloc((size_t)N * 64 * 2);
    unsigned char* xw8 = (unsigned char*)alloc((size_t)(N + 1) * 64);    // layer1 fp8
    unsigned char* xw8b = (unsigned char*)alloc((size_t)(N + 1) * 64);   // layer2 fp8
    unsigned short* xrb = (unsigned short*)alloc((size_t)N * 64 * 2);
    unsigned short* xrb2 = (unsigned short*)alloc((size_t)N * 64 * 2);
    float* pooled = (float*)alloc(4096 * 4);
    // zero region: gcur (256) + done (1), one memset
    int* zbuf = (int*)alloc(257 * 4);
    int* gcur = zbuf;
    int* done = zbuf + 256;

    const int nbBin = (E + CHUNK - 1) / CHUNK;

    hipMemsetAsync(zbuf, 0, 257 * 4, stream);
    bin_gemm1<<<nbBin + 1024, 256, 0, stream>>>(srcp, dstp, coarse, gcur, E, BINS, nbBin,
                                                x, W1, root1, b1, xw8, xrb, N);
    finalize_csr<<<BINS, 256, 0, stream>>>(coarse, gcur, bucket, pstart, degarr, N, BINS);
    aggregate<<<4096, 256, 0, stream>>>(xw8, xrb, pstart, degarr, bucket, h1, N);
    gemm_xwr2<<<1024, 256, 0, stream>>>(h1, W2, root2, b2, xw8b, xrb2, N);
    aggregate<<<4096, 256, 0, stream>>>(xw8b, xrb2, pstart, degarr, bucket, h2, N);
    pool_head<<<64, 256, 0, stream>>>(h2, batch, pooled, done, N,
                                      Wh, bh, Wc, bc, Wo, bo, out);
}

// Round 16
// 280.360 us; speedup vs baseline: 1.0282x; 1.0282x over previous
//
#include <hip/hip_runtime.h>
#include <hip/hip_bf16.h>

// FEAT=EMB=HID=64, VOCAB=32, N_GRAPHS=64. N,E from in_sizes.
// R6: transform-first. R7: binned CSR. R9: padded CSR + mask-free gather.
// R11: fp8 e4m3 gather table (64B rows = 1 line), quarter-wave dword gather.
// R13/R14: gemm1 fused into binning kernel; B-frags self-built from fp32.
// R15 kept: finalize writes pad-tails only. R15's pool_head fusion REVERTED
// (60us fused vs 13us split: head phase inflated VGPR/LDS for all blocks and
// ran at single-block parallelism). R16 = best-known per-stage configs.

typedef __attribute__((ext_vector_type(8))) short short8;
typedef __attribute__((ext_vector_type(4))) float f32x4;
typedef __attribute__((ext_vector_type(2))) float f32x2;

#define RB 9            // 512 nodes per coarse bin
#define MAXBINS 256     // N <= 131072
#define CAP 12288       // coarse per-bin capacity
#define BCAP 14336      // padded per-bin bucket capacity
#define CHUNK 8192      // edges per bin block

__device__ inline float bf2f(unsigned short h) {
    return __uint_as_float(((unsigned int)h) << 16);
}
__device__ inline float bflo(unsigned int u) { return __uint_as_float(u << 16); }
__device__ inline float bfhi(unsigned int u) { return __uint_as_float(u & 0xffff0000u); }
__device__ inline unsigned short f2bf(float f) {
    unsigned int u = __float_as_uint(f);
    u = (u + 0x7fffu + ((u >> 16) & 1u)) >> 16;  // RNE
    return (unsigned short)u;
}

// Self-build MFMA B-fragments from fp32 W (cols 0..63) and R (cols 64..127).
__device__ inline void build_bfrag(const float* __restrict__ W,
                                   const float* __restrict__ R,
                                   int q, int mm, short8 bfrag[8][2]) {
#pragma unroll
    for (int t = 0; t < 8; ++t) {
        const int n = t * 16 + mm;
        const float* P = (n < 64) ? (W + n) : (R + n - 64);
#pragma unroll
        for (int c = 0; c < 2; ++c) {
#pragma unroll
            for (int j = 0; j < 8; ++j) {
                const int k = c * 32 + q * 8 + j;
                bfrag[t][c][j] = (short)f2bf(P[k * 64]);
            }
        }
    }
}

// fp8 epilogue store: lanes mm%4==0 pack 4 n-columns into one dword.
__device__ inline void store_xw_fp8(unsigned char* __restrict__ xw8, int rowbase, int q,
                                    int t, int mm, const f32x4& accT, int N) {
#pragma unroll
    for (int r = 0; r < 4; ++r) {
        const float v0 = accT[r];
        const float v1 = __shfl_down(v0, 1);
        const float v2 = __shfl_down(v0, 2);
        const float v3 = __shfl_down(v0, 3);
        const int orow = rowbase + q * 4 + r;
        if (!(mm & 3) && orow < N) {
            unsigned int u = (unsigned int)__builtin_amdgcn_cvt_pk_fp8_f32(v0, v1, 0, false);
            u = (unsigned int)__builtin_amdgcn_cvt_pk_fp8_f32(v2, v3, (int)u, true);
            *(unsigned int*)&xw8[(size_t)orow * 64 + t * 16 + mm] = u;
        }
    }
}

// ---------------- K1: bin edges (blocks [0,nbBin)) + gemm1 (rest) -----------
__global__ __launch_bounds__(256) void bin_gemm1(const int* __restrict__ src,
                                                 const int* __restrict__ dst,
                                                 unsigned int* __restrict__ coarse,
                                                 int* __restrict__ gcur,
                                                 int E, int BINS, int nbBin,
                                                 const float* __restrict__ x,
                                                 const float* __restrict__ W1,
                                                 const float* __restrict__ R1,
                                                 const float* __restrict__ bias,
                                                 unsigned char* __restrict__ xw8,
                                                 unsigned short* __restrict__ xrb,
                                                 int N) {
    __shared__ int cnt[MAXBINS];
    __shared__ int incl[MAXBINS];
    __shared__ int bstart[MAXBINS];
    __shared__ int bcur[MAXBINS];
    __shared__ int gbase[MAXBINS];
    __shared__ unsigned int stage[CHUNK];
    __shared__ unsigned char binOf[CHUNK];

    const int tid = threadIdx.x;
    if (blockIdx.x >= (unsigned)nbBin) {
        // ---- gemm1 branch: xw8/xrb = x @ [W1|R1] (+b1 in R half) ----
        const int gb = blockIdx.x - nbBin;
        if (gb == 0 && tid < 16)  // zero fp8 row N (dummy target)
            *(unsigned int*)&xw8[(size_t)N * 64 + tid * 4] = 0u;

        const int lane = tid & 63;
        const int q = lane >> 4;
        const int mm = lane & 15;

        short8 bfrag[8][2];
        build_bfrag(W1, R1, q, mm, bfrag);
        float bv[4];
#pragma unroll
        for (int tt = 0; tt < 4; ++tt) bv[tt] = bias[tt * 16 + mm];

        const int wid = tid >> 6;
        const int gw = gb * 4 + wid;
        const int nw = 1024 * 4;
        const int ntiles = N >> 4;

        for (int tile = gw; tile < ntiles; tile += nw) {
            const int row0 = tile << 4;
            const float* ap = &x[(size_t)(row0 + mm) * 64 + q * 8];
            const float4 f0 = *(const float4*)ap;
            const float4 f1 = *(const float4*)(ap + 4);
            const float4 f2 = *(const float4*)(ap + 32);
            const float4 f3 = *(const float4*)(ap + 36);
            short8 a0, a1;
            a0[0] = (short)f2bf(f0.x); a0[1] = (short)f2bf(f0.y);
            a0[2] = (short)f2bf(f0.z); a0[3] = (short)f2bf(f0.w);
            a0[4] = (short)f2bf(f1.x); a0[5] = (short)f2bf(f1.y);
            a0[6] = (short)f2bf(f1.z); a0[7] = (short)f2bf(f1.w);
            a1[0] = (short)f2bf(f2.x); a1[1] = (short)f2bf(f2.y);
            a1[2] = (short)f2bf(f2.z); a1[3] = (short)f2bf(f2.w);
            a1[4] = (short)f2bf(f3.x); a1[5] = (short)f2bf(f3.y);
            a1[6] = (short)f2bf(f3.z); a1[7] = (short)f2bf(f3.w);
            f32x4 acc[8];
#pragma unroll
            for (int t = 0; t < 8; ++t) {
                acc[t] = (f32x4){0.f, 0.f, 0.f, 0.f};
                acc[t] = __builtin_amdgcn_mfma_f32_16x16x32_bf16(a0, bfrag[t][0], acc[t], 0, 0, 0);
                acc[t] = __builtin_amdgcn_mfma_f32_16x16x32_bf16(a1, bfrag[t][1], acc[t], 0, 0, 0);
            }
#pragma unroll
            for (int t = 0; t < 4; ++t) store_xw_fp8(xw8, row0, q, t, mm, acc[t], N);
#pragma unroll
            for (int t = 4; t < 8; ++t) {
#pragma unroll
                for (int r = 0; r < 4; ++r) {
                    const float v = acc[t][r] + bv[t - 4];
                    const float vn = __shfl_down(v, 1);
                    if (!(mm & 1)) {
                        const unsigned int u = (unsigned int)f2bf(v) | ((unsigned int)f2bf(vn) << 16);
                        *(unsigned int*)&xrb[(size_t)(row0 + q * 4 + r) * 64 + (t - 4) * 16 + mm] = u;
                    }
                }
            }
        }
        return;
    }

    // ---- binning branch ----
    const int chunk0 = blockIdx.x * CHUNK;
    int myS[32], myD[32];
#pragma unroll
    for (int k = 0; k < 32; ++k) {
        const int idx = chunk0 + k * 256 + tid;
        if (idx < E) { myS[k] = src[idx]; myD[k] = dst[idx]; }
        else myD[k] = -1;
    }
    cnt[tid] = 0;
    __syncthreads();
#pragma unroll
    for (int k = 0; k < 32; ++k)
        if (myD[k] >= 0) atomicAdd(&cnt[myD[k] >> RB], 1);
    __syncthreads();
    incl[tid] = cnt[tid];
    __syncthreads();
    for (int off = 1; off < 256; off <<= 1) {
        int t = (tid >= off) ? incl[tid - off] : 0;
        __syncthreads();
        incl[tid] += t;
        __syncthreads();
    }
    bstart[tid] = incl[tid] - cnt[tid];
    bcur[tid] = incl[tid] - cnt[tid];
    __syncthreads();
#pragma unroll
    for (int k = 0; k < 32; ++k) {
        if (myD[k] >= 0) {
            const int b = myD[k] >> RB;
            const int pos = atomicAdd(&bcur[b], 1);
            stage[pos] = (unsigned int)myS[k] | ((unsigned int)(myD[k] & ((1 << RB) - 1)) << 17);
            binOf[pos] = (unsigned char)b;
        }
    }
    __syncthreads();
    if (tid < BINS && cnt[tid] > 0)
        gbase[tid] = tid * CAP + atomicAdd(&gcur[tid], cnt[tid]);
    __syncthreads();
    int total = E - chunk0;
    if (total > CHUNK) total = CHUNK;
    for (int idx = tid; idx < total; idx += 256) {
        const int b = binOf[idx];
        coarse[gbase[b] + (idx - bstart[b])] = stage[idx];
    }
}

// ---------------- K2: finalize padded CSR (one block per bin) ---------------
// Pad-tails written directly (disjoint from scatter positions).
__global__ __launch_bounds__(256) void finalize_csr(const unsigned int* __restrict__ coarse,
                                                    const int* __restrict__ gcur,
                                                    int* __restrict__ bucket,
                                                    int* __restrict__ pstart,
                                                    int* __restrict__ degarr,
                                                    int N, int BINS) {
    __shared__ int ncnt[512];
    __shared__ int pexcl[512];
    __shared__ int ncur[512];
    __shared__ int s2[256];

    const int tid = threadIdx.x;
    const int b = blockIdx.x;
    const int cb = gcur[b];
    const int base = b * BCAP;
    const unsigned int* reg = coarse + (size_t)b * CAP;
    const int node0 = b << RB;
    int nloc = N - node0;
    if (nloc > 512) nloc = 512;

    ncnt[tid] = 0; ncnt[tid + 256] = 0;
    __syncthreads();
    for (int idx = tid; idx < cb; idx += 256)
        atomicAdd(&ncnt[reg[idx] >> 17], 1);
    __syncthreads();
    const int p0 = (ncnt[2 * tid] + 15) & ~15;
    const int p1 = (ncnt[2 * tid + 1] + 15) & ~15;
    s2[tid] = p0 + p1;
    __syncthreads();
    for (int off = 1; off < 256; off <<= 1) {
        int t = (tid >= off) ? s2[tid - off] : 0;
        __syncthreads();
        s2[tid] += t;
        __syncthreads();
    }
    const int pairExcl = s2[tid] - (p0 + p1);
    pexcl[2 * tid] = pairExcl;
    pexcl[2 * tid + 1] = pairExcl + p0;
    ncur[2 * tid] = pairExcl;
    ncur[2 * tid + 1] = pairExcl + p0;
    __syncthreads();
    for (int i = tid; i < nloc; i += 256) {
        pstart[node0 + i] = base + pexcl[i];
        degarr[node0 + i] = ncnt[i];
        const int dg = ncnt[i];
        const int pd = (dg + 15) & ~15;
        for (int j = dg; j < pd; ++j) bucket[base + pexcl[i] + j] = N;
    }
    for (int idx = tid; idx < cb; idx += 256) {
        const unsigned int e = reg[idx];
        const int p = atomicAdd(&ncur[e >> 17], 1);
        bucket[base + p] = (int)(e & 0x1FFFFu);
    }
}

// ---------------- K3/K5: aggregate: out = relu(mean_j xW[j] + xRb[i]) -------
__global__ __launch_bounds__(256) void aggregate(const unsigned char* __restrict__ xw8,
                                                 const unsigned short* __restrict__ xrb,
                                                 const int* __restrict__ pstart,
                                                 const int* __restrict__ degarr,
                                                 const int* __restrict__ bucket,
                                                 unsigned short* __restrict__ outb,
                                                 int N) {
    const int lane = threadIdx.x & 63;
    const int quarter = lane >> 4;
    const int fl = lane & 15;
    const int wid = threadIdx.x >> 6;
    const int gw = blockIdx.x * 4 + wid;
    const int nw = gridDim.x * 4;

    for (int i = gw; i < N; i += nw) {
        const int r0 = pstart[i];
        const int dg = degarr[i];
        const int pdeg = (dg + 15) & ~15;
        float a0 = 0.f, a1 = 0.f, a2 = 0.f, a3 = 0.f;
        for (int base = 0; base < pdeg; base += 64) {
            const int rem = pdeg - base;
            const int s = (lane < rem) ? bucket[r0 + base + lane] : N;
            const int mm = rem < 64 ? rem : 64;
            for (int t = 0; t < mm; t += 16) {
                unsigned int u[4];
#pragma unroll
                for (int p = 0; p < 4; ++p) {
                    const int rr = __shfl(s, t + 4 * p + quarter);
                    u[p] = *(const unsigned int*)&xw8[(size_t)rr * 64 + fl * 4];
                }
#pragma unroll
                for (int p = 0; p < 4; ++p) {
                    const f32x2 lo = __builtin_amdgcn_cvt_pk_f32_fp8(u[p], false);
                    const f32x2 hi = __builtin_amdgcn_cvt_pk_f32_fp8(u[p], true);
                    a0 += lo.x; a1 += lo.y; a2 += hi.x; a3 += hi.y;
                }
            }
        }
        a0 += __shfl_xor(a0, 16); a1 += __shfl_xor(a1, 16);
        a2 += __shfl_xor(a2, 16); a3 += __shfl_xor(a3, 16);
        a0 += __shfl_xor(a0, 32); a1 += __shfl_xor(a1, 32);
        a2 += __shfl_xor(a2, 32); a3 += __shfl_xor(a3, 32);

        const float inv = 1.0f / (float)(dg > 0 ? dg : 1);
        if (quarter == 0) {
            const uint2 ur = *(const uint2*)&xrb[(size_t)i * 64 + fl * 4];
            const float o0 = fmaxf(a0 * inv + bflo(ur.x), 0.f);
            const float o1 = fmaxf(a1 * inv + bfhi(ur.x), 0.f);
            const float o2 = fmaxf(a2 * inv + bflo(ur.y), 0.f);
            const float o3 = fmaxf(a3 * inv + bfhi(ur.y), 0.f);
            uint2 w;
            w.x = (unsigned int)f2bf(o0) | ((unsigned int)f2bf(o1) << 16);
            w.y = (unsigned int)f2bf(o2) | ((unsigned int)f2bf(o3) << 16);
            *(uint2*)&outb[(size_t)i * 64 + fl * 4] = w;
        }
    }
}

// ---------------- K4: gemm layer 2 (bf16 A from h1, self-built B) -----------
__global__ __launch_bounds__(256) void gemm_xwr2(const unsigned short* __restrict__ xin,
                                                 const float* __restrict__ W2,
                                                 const float* __restrict__ R2,
                                                 const float* __restrict__ bias,
                                                 unsigned char* __restrict__ xw8,
                                                 unsigned short* __restrict__ xrb,
                                                 int M) {
    if (blockIdx.x == 0 && threadIdx.x < 16)
        *(unsigned int*)&xw8[(size_t)M * 64 + threadIdx.x * 4] = 0u;

    const int lane = threadIdx.x & 63;
    const int q = lane >> 4;
    const int mm = lane & 15;

    short8 bfrag[8][2];
    build_bfrag(W2, R2, q, mm, bfrag);
    float bv[4];
#pragma unroll
    for (int tt = 0; tt < 4; ++tt) bv[tt] = bias[tt * 16 + mm];

    const int wid = threadIdx.x >> 6;
    const int gw = blockIdx.x * 4 + wid;
    const int nw = gridDim.x * 4;
    const int ntiles = M >> 4;

    for (int tile = gw; tile < ntiles; tile += nw) {
        const int row0 = tile << 4;
        const short8 a0 = *(const short8*)&xin[(size_t)(row0 + mm) * 64 + q * 8];
        const short8 a1 = *(const short8*)&xin[(size_t)(row0 + mm) * 64 + 32 + q * 8];
        f32x4 acc[8];
#pragma unroll
        for (int t = 0; t < 8; ++t) {
            acc[t] = (f32x4){0.f, 0.f, 0.f, 0.f};
            acc[t] = __builtin_amdgcn_mfma_f32_16x16x32_bf16(a0, bfrag[t][0], acc[t], 0, 0, 0);
            acc[t] = __builtin_amdgcn_mfma_f32_16x16x32_bf16(a1, bfrag[t][1], acc[t], 0, 0, 0);
        }
#pragma unroll
        for (int t = 0; t < 4; ++t) store_xw_fp8(xw8, row0, q, t, mm, acc[t], M);
#pragma unroll
        for (int t = 4; t < 8; ++t) {
#pragma unroll
            for (int r = 0; r < 4; ++r) {
                const float v = acc[t][r] + bv[t - 4];
                const float vn = __shfl_down(v, 1);
                if (!(mm & 1)) {
                    const unsigned int u = (unsigned int)f2bf(v) | ((unsigned int)f2bf(vn) << 16);
                    *(unsigned int*)&xrb[(size_t)(row0 + q * 4 + r) * 64 + (t - 4) * 16 + mm] = u;
                }
            }
        }
    }
}

// ---------------- K6: pooling (per-graph block, self-computed bounds) -------
__global__ __launch_bounds__(256) void pool_kernel(const unsigned short* __restrict__ h,
                                                   const int* __restrict__ batch,
                                                   float* __restrict__ pooled, int N) {
    __shared__ float red[16][64];
    __shared__ int bnds[2];
    const int gph = blockIdx.x;
    if (threadIdx.x < 2) {
        const int target = gph + threadIdx.x;
        int lo = 0, hi = N;
        while (lo < hi) {
            int mid = (lo + hi) >> 1;
            if (batch[mid] < target) lo = mid + 1; else hi = mid;
        }
        bnds[threadIdx.x] = lo;
    }
    __syncthreads();
    const int r0 = bnds[0], r1 = bnds[1];
    const int f = threadIdx.x & 15;
    const int r = threadIdx.x >> 4;
    float4 acc = {0.f, 0.f, 0.f, 0.f};
    for (int row = r0 + r; row < r1; row += 16) {
        const ushort4 v = *(const ushort4*)&h[(size_t)row * 64 + f * 4];
        acc.x += bf2f(v.x); acc.y += bf2f(v.y);
        acc.z += bf2f(v.z); acc.w += bf2f(v.w);
    }
    red[r][f * 4 + 0] = acc.x; red[r][f * 4 + 1] = acc.y;
    red[r][f * 4 + 2] = acc.z; red[r][f * 4 + 3] = acc.w;
    __syncthreads();
    if (threadIdx.x < 64) {
        float s = 0.f;
        for (int j = 0; j < 16; ++j) s += red[j][threadIdx.x];
        const int cnt = r1 - r0;
        const float invc = 1.0f / (float)(cnt > 0 ? cnt : 1);
        pooled[gph * 64 + threadIdx.x] = s * invc;
    }
}

// ---------------- K7: heads ----------------
__global__ __launch_bounds__(256) void head_kernel(const float* __restrict__ pooled,
                                                   const float* __restrict__ Wh,
                                                   const float* __restrict__ bh,
                                                   const float* __restrict__ Wc,
                                                   const float* __restrict__ bc,
                                                   const float* __restrict__ Wo,
                                                   const float* __restrict__ bo,
                                                   float* __restrict__ out) {
    __shared__ float pm[4096];
    __shared__ float hid[4096];
    __shared__ float lg[2048];
    const int t = threadIdx.x;

    for (int idx = t; idx < 4096; idx += 256) pm[idx] = pooled[idx];
    __syncthreads();

    for (int idx = t; idx < 4096; idx += 256) {
        int g = idx >> 6, o = idx & 63;
        float ah = bh[o], ac = bc[o];
        for (int k = 0; k < 64; ++k) {
            float p = pm[(g << 6) + k];
            ah += p * Wh[k * 64 + o];
            ac += p * Wc[k * 64 + o];
        }
        hid[idx] = ah;
        out[2048 + idx] = ah;
        out[6144 + idx] = ac;
    }
    __syncthreads();

    for (int idx = t; idx < 2048; idx += 256) {
        int g = idx >> 5, v = idx & 31;
        float a = bo[v];
        for (int k = 0; k < 64; ++k) a += hid[(g << 6) + k] * Wo[k * 32 + v];
        lg[idx] = a;
    }
    __syncthreads();

    if (t < 64) {
        float mx = -3.4e38f;
        for (int v = 0; v < 32; ++v) mx = fmaxf(mx, lg[(t << 5) + v]);
        float s = 0.f;
        for (int v = 0; v < 32; ++v) s += expf(lg[(t << 5) + v] - mx);
        float lse = mx + logf(s);
        for (int v = 0; v < 32; ++v) out[(t << 5) + v] = lg[(t << 5) + v] - lse;
    }
}

extern "C" void kernel_launch(void* const* d_in, const int* in_sizes, int n_in,
                              void* d_out, int out_size, void* d_ws, size_t ws_size,
                              hipStream_t stream) {
    const float* x = (const float*)d_in[0];
    const int* ei = (const int*)d_in[1];
    const int* batch = (const int*)d_in[2];
    const float* W1 = (const float*)d_in[3];
    const float* root1 = (const float*)d_in[4];
    const float* b1 = (const float*)d_in[5];
    const float* W2 = (const float*)d_in[6];
    const float* root2 = (const float*)d_in[7];
    const float* b2 = (const float*)d_in[8];
    const float* Wh = (const float*)d_in[9];
    const float* bh = (const float*)d_in[10];
    const float* Wc = (const float*)d_in[11];
    const float* bc = (const float*)d_in[12];
    const float* Wo = (const float*)d_in[13];
    const float* bo = (const float*)d_in[14];
    float* out = (float*)d_out;

    const int N = in_sizes[0] / 64;
    const int E = in_sizes[1] / 2;
    const int* srcp = ei;
    const int* dstp = ei + E;
    const int BINS = (N + (1 << RB) - 1) >> RB;

    char* ws = (char*)d_ws;
    size_t off = 0;
    auto alloc = [&](size_t bytes) -> void* {
        void* p = ws + off;
        off += (bytes + 255) & ~(size_t)255;
        return p;
    };
    int* pstart = (int*)alloc((size_t)N * 4);
    int* degarr = (int*)alloc((size_t)N * 4);
    int* bucket = (int*)alloc(((size_t)BINS * BCAP + 256) * 4);
    unsigned int* coarse = (unsigned int*)alloc((size_t)BINS * CAP * 4);
    unsigned short* h1 = (unsigned short*)alloc((size_t)N * 64 * 2);
    unsigned short* h2 = (unsigned short*)alloc((size_t)N * 64 * 2);
    unsigned char* xw8 = (unsigned char*)alloc((size_t)(N + 1) * 64);    // layer1 fp8
    unsigned char* xw8b = (unsigned char*)alloc((size_t)(N + 1) * 64);   // layer2 fp8
    unsigned short* xrb = (unsigned short*)alloc((size_t)N * 64 * 2);
    unsigned short* xrb2 = (unsigned short*)alloc((size_t)N * 64 * 2);
    float* pooled = (float*)alloc(4096 * 4);
    int* gcur = (int*)alloc(MAXBINS * 4);

    const int nbBin = (E + CHUNK - 1) / CHUNK;

    hipMemsetAsync(gcur, 0, MAXBINS * 4, stream);
    bin_gemm1<<<nbBin + 1024, 256, 0, stream>>>(srcp, dstp, coarse, gcur, E, BINS, nbBin,
                                                x, W1, root1, b1, xw8, xrb, N);
    finalize_csr<<<BINS, 256, 0, stream>>>(coarse, gcur, bucket, pstart, degarr, N, BINS);
    aggregate<<<4096, 256, 0, stream>>>(xw8, xrb, pstart, degarr, bucket, h1, N);
    gemm_xwr2<<<1024, 256, 0, stream>>>(h1, W2, root2, b2, xw8b, xrb2, N);
    aggregate<<<4096, 256, 0, stream>>>(xw8b, xrb2, pstart, degarr, bucket, h2, N);
    pool_kernel<<<64, 256, 0, stream>>>(h2, batch, pooled, N);
    head_kernel<<<1, 256, 0, stream>>>(pooled, Wh, bh, Wc, bc, Wo, bo, out);
}